// Round 10
// baseline (307.687 us; speedup 1.0000x reference)
//
#include <hip/hip_runtime.h>
#include <hip/hip_bf16.h>
#include <stdint.h>

#define TSTEPS 4

typedef __bf16 bf16_t;
typedef __attribute__((ext_vector_type(8))) __bf16 bf16x8;
typedef __attribute__((ext_vector_type(16))) float f32x16;
typedef __attribute__((ext_vector_type(4))) unsigned short ushort4v;

union frag_u { bf16x8 v; uint32_t d[4]; unsigned short u[8]; };

// gfx9 s_waitcnt imm: vm [3:0]|[15:14]; exp [6:4]; lgkm [11:8].
#define WT_VM10_LG0 0x07A   // vmcnt(10) lgkmcnt(0)
#define WT_VM8_LG0  0x078   // vmcnt(8)  lgkmcnt(0)
#define WT_VM10     0xF7A   // vmcnt(10)
#define WT_VM0_LG0  0x070   // full drain (tail)

// ---------------------------------------------------------------------------
// R26 = R25 with 2-kb PHASES: 16 MFMAs (512 matrix-cyc) per vmcnt+barrier,
// halving sync points (64 -> 32). Rationale: five structures (R18/21/22/24/
// 25) all pin at 47% MfmaUtil with ~565 cyc/wave-step of which 256 = MFMA;
// the ~310-cyc residual is a fixed per-step tax (VALU + wait/issue
// serialization) immune to prefetch depth, barriers, and byte count.
// Amortize it: 2 kb per phase -> predicted period ~820 cyc for 512 matrix.
// LDS: 8-slot x 4KB B-ring (stage 2 kb, 2 phases ahead). A: reg-prefetch
// one phase ahead (8 loads/phase, 2 fm slots of 2 kb each, static parity).
// Counted waits: vmcnt(10)+lgkm(0) per phase (drains prev phase's 10 ops).
// Fused mean-over-L in LAST epilogue kept (R24 win).
// Spike bytes 0x3F -> v_perm high-byte = bf16 0.5; B pre-doubled (exact
// exponent bump) so products are bitwise 1.0*w (R19/R21/R22-proven).
// A layout: [m_blk32][kb16][t][row0..31][16 bytes], byte = 0x00 / 0x3F.
// B-frag layout: packet ((n>>5)*NKB + (k>>4))*512 + ((n&31)+32*((k>>3)&1))*8
// + (k&7), bf16, value = 2*w_hi / 2*w_lo.
// ---------------------------------------------------------------------------

// ---------------------------------------------------------------------------
// Stage 1: input LIF encoder -> spike 0x3F bytes. C=128. XLA-exact LIF.
// ---------------------------------------------------------------------------
__global__ void spike_encode_i8(const float* __restrict__ x,
                                uint4* __restrict__ s1)
{
    const int C = 128;
    int tid = blockIdx.x * blockDim.x + threadIdx.x;  // 65536 = 256*8*32
    int row = tid & 31;
    int kb  = (tid >> 5) & 7;
    int m_blk = tid >> 8;
    int m = m_blk * 32 + row;
    const float* px = x + (size_t)m * C + kb * 16;
    float xv[16];
#pragma unroll
    for (int j = 0; j < 16; j += 4) {
        float4 t4 = *(const float4*)(px + j);
        xv[j] = t4.x; xv[j+1] = t4.y; xv[j+2] = t4.z; xv[j+3] = t4.w;
    }
    float v[16];
#pragma unroll
    for (int j = 0; j < 16; ++j) v[j] = 0.0f;
#pragma unroll
    for (int t = 0; t < TSTEPS; ++t) {
        uint32_t dw[4] = {0u, 0u, 0u, 0u};
#pragma unroll
        for (int j = 0; j < 16; ++j) {
            float vv = __fadd_rn(v[j], __fmul_rn(__fsub_rn(xv[j], v[j]), 0.5f));
            bool sp = (vv >= 1.0f);
            dw[j >> 2] |= sp ? (0x3Fu << ((j & 3) * 8)) : 0u;
            v[j] = sp ? 0.0f : vv;
        }
        uint4 o; o.x = dw[0]; o.y = dw[1]; o.z = dw[2]; o.w = dw[3];
        s1[((size_t)(m_blk * 8 + kb) * 4 + t) * 32 + row] = o;
    }
}

// ---------------------------------------------------------------------------
// Weight prep: W [K][N] fp32 -> 2*hi / 2*lo bf16 split in B-frag layout.
// ---------------------------------------------------------------------------
__global__ void split_transpose_all(const float* __restrict__ enc_W,
                                    const float* __restrict__ W_cells,
                                    bf16_t* __restrict__ W1h, bf16_t* __restrict__ W1l,
                                    bf16_t* __restrict__ W2h, bf16_t* __restrict__ W2l,
                                    bf16_t* __restrict__ W3h, bf16_t* __restrict__ W3l)
{
    const int N = 1024;
    const float* W;
    bf16_t *hi, *lo;
    int K;
    if (blockIdx.z == 0) {
        if (blockIdx.x >= 4) return;
        W = enc_W; hi = W1h; lo = W1l; K = 128;
    } else if (blockIdx.z == 1) {
        W = W_cells; hi = W2h; lo = W2l; K = 1024;
    } else {
        W = W_cells + (size_t)1024 * 1024; hi = W3h; lo = W3l; K = 1024;
    }
    const int NKB = K >> 4;
    __shared__ float tile[32][33];
    int k0 = blockIdx.x * 32, n0 = blockIdx.y * 32;
    int tx = threadIdx.x & 31, ty = threadIdx.x >> 5;
    for (int kk = ty; kk < 32; kk += 8)
        tile[kk][tx] = W[(size_t)(k0 + kk) * N + n0 + tx];
    __syncthreads();

    const int nn = tx;
    const int oc = ty;            // 0..7
    const int o2 = oc & 3;        // k-octet
    const bool isLo = (oc >> 2) != 0;
    const int kblk = (k0 >> 4) + (o2 >> 1);
    const int lane_in_packet = nn + 32 * (o2 & 1);

    frag_u f;
#pragma unroll
    for (int j = 0; j < 8; ++j) {
        float wv = tile[o2 * 8 + j][nn];
        bf16_t h = (bf16_t)wv;                          // original hi rounding
        bf16_t l = (bf16_t)(wv - (float)h);             // original lo rounding
        f.v[j] = isLo ? (bf16_t)(2.0f * (float)l)       // exact doubling
                      : (bf16_t)(2.0f * (float)h);
    }
    bf16_t* dst = (isLo ? lo : hi)
        + ((size_t)((n0 + nn) >> 5) * NKB + kblk) * 512 + lane_in_packet * 8;
    *(bf16x8*)dst = f.v;
}

// ---------------------------------------------------------------------------
// Fused MFMA GEMM + multistep LIF. R26: 2-kb phases (16 MFMAs per sync),
// 8-slot LDS B-ring staged 2 phases ahead, reg A one phase ahead,
// counted waits, fused mean (LAST).
// ---------------------------------------------------------------------------
template <int K, bool LAST>
__global__ __launch_bounds__(256, 3)
void gemm_lif_mfma(const uint8_t* __restrict__ Abytes,
                   const bf16_t* __restrict__ Bh,
                   const bf16_t* __restrict__ Bl,
                   const float* __restrict__ bias,
                   uint8_t* __restrict__ Sbytes,
                   float* __restrict__ Out,
                   int M, int N)
{
    constexpr int NKB = K >> 4;                 // 8 or 64
    constexpr int NP  = NKB >> 1;               // phases (2 kb each), even
    __shared__ __align__(16) uint8_t ldsB[8][4096];      // 8-slot B ring
    __shared__ __align__(8) unsigned short sh[4][256];   // epilogue, per-wave

    const int tid = threadIdx.x;
    const int lane = tid & 63;
    const int wid = tid >> 6;
    const int l31 = lane & 31;
    const int half = lane >> 5;

    // XCD-locality swizzle (R18): XCD x owns m_t in [x*16, x*16+16);
    // walk nh(2) x mloc(16) x n8(8). Bijective.
    const int bid = blockIdx.x;
    const int xcd = bid & 7;
    const int j   = bid >> 3;                   // 0..255
    const int nh   = j >> 7;                    // 0..1
    const int r    = j & 127;
    const int mloc = r >> 3;                    // 0..15
    const int n_t  = nh * 8 + (r & 7);          // 0..15
    const int m_t  = xcd * 16 + mloc;           // 0..127

    const int m0 = m_t * 64, n0 = n_t * 64;
    const int wave_m = (wid & 1) * 32;
    const int wave_n = (wid >> 1) * 32;
    const int m_blk = (m0 + wave_m) >> 5;

    const uint8_t* pA = Abytes + (size_t)m_blk * NKB * 4 * 512 + l31 * 16 + half * 8;

    // B staging: wave wid stages chunk wid = (n_local = wid>>1, plane = wid&1)
    // at ring offset (kb&7)*4096 + wid*1024. Source: 1KB lane-linear packet.
    const uint8_t* stage_src = (const uint8_t*)(((wid & 1) ? Bl : Bh)
        + (size_t)((n0 >> 5) + (wid >> 1)) * NKB * 512) + (lane << 4);
    uint8_t* ldsStage = &ldsB[0][0] + (wid << 10);
    // Consumer: wave wid reads n_local = wid>>1: hi at +0, lo at +1024.
    const uint8_t* ldsRd = &ldsB[0][0] + ((wid >> 1) << 11) + (lane << 4);

    f32x16 acc[TSTEPS];
#pragma unroll
    for (int t = 0; t < TSTEPS; ++t)
        for (int rr = 0; rr < 16; ++rr) acc[t][rr] = 0.0f;

    uint2 fm[2][2][4];    // [slot][kb-in-phase][t]
    bf16x8 cfh0, cfl0, cfh1, cfl1;

#define STAGE1(kb_)                                                           \
    __builtin_amdgcn_global_load_lds(                                         \
        (const __attribute__((address_space(1))) uint32_t*)                   \
            (stage_src + (size_t)(kb_) * 1024),                               \
        (__attribute__((address_space(3))) uint32_t*)                         \
            (ldsStage + (((kb_) & 7) << 12)),                                 \
        16, 0, 0);

#define LOADA2(kb_, s_) {                                                    \
        fm[s_][0][0] = *(const uint2*)(pA + ((size_t)(kb_) * 4 + 0) * 512);  \
        fm[s_][0][1] = *(const uint2*)(pA + ((size_t)(kb_) * 4 + 1) * 512);  \
        fm[s_][0][2] = *(const uint2*)(pA + ((size_t)(kb_) * 4 + 2) * 512);  \
        fm[s_][0][3] = *(const uint2*)(pA + ((size_t)(kb_) * 4 + 3) * 512);  \
        fm[s_][1][0] = *(const uint2*)(pA + ((size_t)(kb_) * 4 + 4) * 512);  \
        fm[s_][1][1] = *(const uint2*)(pA + ((size_t)(kb_) * 4 + 5) * 512);  \
        fm[s_][1][2] = *(const uint2*)(pA + ((size_t)(kb_) * 4 + 6) * 512);  \
        fm[s_][1][3] = *(const uint2*)(pA + ((size_t)(kb_) * 4 + 7) * 512);  \
    }

#define FRAGRD(kb_) {                                                        \
        cfh0 = *(const bf16x8*)(ldsRd + (((kb_) & 7) << 12));                \
        cfl0 = *(const bf16x8*)(ldsRd + (((kb_) & 7) << 12) + 1024);         \
        cfh1 = *(const bf16x8*)(ldsRd + ((((kb_) + 1) & 7) << 12));          \
        cfl1 = *(const bf16x8*)(ldsRd + ((((kb_) + 1) & 7) << 12) + 1024);   \
    }

// byte 0x3F -> high byte of each 16-bit half = 0x3F00 = bf16 0.5 (1 perm/dw)
#define EXPANDF(a_, f_) {                                                    \
        (f_).d[0] = __builtin_amdgcn_perm((a_).x, 0u, 0x05000400u);          \
        (f_).d[1] = __builtin_amdgcn_perm((a_).x, 0u, 0x07000600u);          \
        (f_).d[2] = __builtin_amdgcn_perm((a_).y, 0u, 0x05000400u);          \
        (f_).d[3] = __builtin_amdgcn_perm((a_).y, 0u, 0x07000600u);          \
    }

#define MFMAS(s_, i_, fhv_, flv_) {                                          \
        frag_u af0, af1, af2, af3;                                           \
        EXPANDF(fm[s_][i_][0], af0);                                         \
        EXPANDF(fm[s_][i_][1], af1);                                         \
        EXPANDF(fm[s_][i_][2], af2);                                         \
        EXPANDF(fm[s_][i_][3], af3);                                         \
        acc[0] = __builtin_amdgcn_mfma_f32_32x32x16_bf16(af0.v, fhv_, acc[0], 0, 0, 0); \
        acc[1] = __builtin_amdgcn_mfma_f32_32x32x16_bf16(af1.v, fhv_, acc[1], 0, 0, 0); \
        acc[2] = __builtin_amdgcn_mfma_f32_32x32x16_bf16(af2.v, fhv_, acc[2], 0, 0, 0); \
        acc[3] = __builtin_amdgcn_mfma_f32_32x32x16_bf16(af3.v, fhv_, acc[3], 0, 0, 0); \
        acc[0] = __builtin_amdgcn_mfma_f32_32x32x16_bf16(af0.v, flv_, acc[0], 0, 0, 0); \
        acc[1] = __builtin_amdgcn_mfma_f32_32x32x16_bf16(af1.v, flv_, acc[1], 0, 0, 0); \
        acc[2] = __builtin_amdgcn_mfma_f32_32x32x16_bf16(af2.v, flv_, acc[2], 0, 0, 0); \
        acc[3] = __builtin_amdgcn_mfma_f32_32x32x16_bf16(af3.v, flv_, acc[3], 0, 0, 0); \
    }

// Phase p_ (fm slot s_ = p_&1): computes kb 2p,2p+1; stages kb 2p+4,2p+5
// (2 phases ahead, ring slots (2p+4)&7,(2p+5)&7); loads A for next phase
// into slot s_^1. vmcnt(10)+lgkm(0): 10 outstanding = this phase's
// (2 stage + 8 A) -> drains ALL of prev phase's ops, incl. stage(2p+2,2p+3)
// (needed by FRAGRD after this barrier) and A(2p,2p+1). Ring overwrite of
// slot (2p+4)&7 (last held kb 2p-4): its ds_reads drained >= 2 barriers ago.
#define PHASE(p_, s_) {                                                      \
        STAGE1(2 * (p_) + 4);                                                \
        STAGE1(2 * (p_) + 5);                                                \
        LOADA2(2 * (p_) + 2, (s_) ^ 1);                                      \
        __builtin_amdgcn_s_waitcnt(WT_VM10_LG0);                             \
        asm volatile("" ::: "memory");                                       \
        MFMAS(s_, 0, cfh0, cfl0);                                            \
        MFMAS(s_, 1, cfh1, cfl1);                                            \
        __builtin_amdgcn_s_barrier();                                        \
        asm volatile("" ::: "memory");                                       \
        FRAGRD(2 * (p_) + 2);                                                \
    }

    // Prologue: stage kb 0..3 (phases 0,1), A(phase0) into slot 0.
    STAGE1(0); STAGE1(1); STAGE1(2); STAGE1(3);
    LOADA2(0, 0);
    __builtin_amdgcn_s_waitcnt(WT_VM10);  // drains stage(0),stage(1)
    asm volatile("" ::: "memory");
    __builtin_amdgcn_s_barrier();
    asm volatile("" ::: "memory");
    FRAGRD(0);

    for (int p = 0; p < NP - 2; p += 2) {
        PHASE(p + 0, 0);
        PHASE(p + 1, 1);
    }
    // Phase NP-2 (slot 0): nothing more to stage; load A for last phase.
    LOADA2(NKB - 2, 1);
    __builtin_amdgcn_s_waitcnt(WT_VM8_LG0);   // drains prev phase's 10
    asm volatile("" ::: "memory");
    MFMAS(0, 0, cfh0, cfl0);
    MFMAS(0, 1, cfh1, cfl1);
    __builtin_amdgcn_s_barrier();
    asm volatile("" ::: "memory");
    FRAGRD(NKB - 2);
    // Phase NP-1 (slot 1): full drain.
    __builtin_amdgcn_s_waitcnt(WT_VM0_LG0);
    asm volatile("" ::: "memory");
    MFMAS(1, 0, cfh0, cfl0);
    MFMAS(1, 1, cfh1, cfl1);

#undef PHASE
#undef MFMAS
#undef EXPANDF
#undef FRAGRD
#undef LOADA2
#undef STAGE1

    // --- LIF epilogue: t-scan in registers (XLA-exact arithmetic) ---
    const float bv = bias[n0 + wave_n + l31];
    f32x16 vmem;
#pragma unroll
    for (int rr = 0; rr < 16; ++rr) vmem[rr] = 0.0f;
    uint64_t bits = 0ull;
    unsigned short* myt = &sh[wid][0];          // [row][kb][t] = [32][2][4]

    const int NKBo = N >> 4;
    const int kbase = (n0 + wave_n) >> 4;

    for (int t = 0; t < TSTEPS; ++t) {
#pragma unroll
        for (int rr = 0; rr < 16; ++rr) {
            float y = __fadd_rn(acc[t][rr], bv);
            float vv = vmem[rr];
            vv = __fadd_rn(vv, __fmul_rn(__fsub_rn(y, vv), 0.5f));
            bool sp = (vv >= 1.0f);
            vmem[rr] = sp ? 0.0f : vv;
            if (LAST) {
                bits |= sp ? (1ull << (rr * 4 + t)) : 0ull;
            } else {
                unsigned long long b = __ballot(sp);
                if (l31 == 0) {
                    uint32_t hb = (uint32_t)(b >> (half * 32));
                    int rowi = (rr & 3) + 8 * (rr >> 2) + 4 * half;
                    myt[(rowi * 2 + 0) * 4 + t] = (unsigned short)hb;
                    myt[(rowi * 2 + 1) * 4 + t] = (unsigned short)(hb >> 16);
                }
            }
        }
    }

    if (LAST) {
        // Out writes + fused mean-over-L. All values multiples of 2^-11,
        // totals <= 1 -> fp32 atomics exact and order-independent.
        float psum = 0.0f;
#pragma unroll
        for (int rr = 0; rr < 16; ++rr) {
            int m_r = (rr & 3) + 8 * (rr >> 2) + 4 * half;
            int m = m0 + wave_m + m_r;
            int n = n0 + wave_n + l31;
            int cnt = __popc((unsigned)((bits >> (rr * 4)) & 0xFull));
            float val = 0.25f * (float)cnt;
            Out[(size_t)m * N + n] = val;
            psum += val;                       // exact: multiples of 0.25
        }
        // combine the two halves (same n, other 16 m's of the 32-row blk)
        psum += __shfl_xor(psum, 32, 64);
        if (half == 0) {
            float* out2 = Out + (size_t)M * N;
            int b = m0 >> 9;                   // m0 multiple of 64; L = 512
            int n = n0 + wave_n + l31;
            atomicAdd(out2 + (size_t)b * N + n, psum * (1.0f / 512.0f));
        }
    } else {
        // Emit next-stage A bytes: 0x00 / 0x3F.
        const ushort4v pk = *(const ushort4v*)&myt[(l31 * 2 + half) * 4];
#pragma unroll
        for (int t = 0; t < TSTEPS; ++t) {
            uint32_t m16 = pk[t];
            uint4 o;
            o.x = (((m16      ) & 0xFu) * 0x00204081u & 0x01010101u) * 0x3Fu;
            o.y = (((m16 >>  4) & 0xFu) * 0x00204081u & 0x01010101u) * 0x3Fu;
            o.z = (((m16 >>  8) & 0xFu) * 0x00204081u & 0x01010101u) * 0x3Fu;
            o.w = (((m16 >> 12) & 0xFu) * 0x00204081u & 0x01010101u) * 0x3Fu;
            *(uint4*)(Sbytes + ((((size_t)m_blk * NKBo + kbase + half) * 4 + t)
                                * 32 + l31) * 16) = o;
        }
    }
}

// ---------------------------------------------------------------------------
// Zero out2 (graph-capture-safe replacement for hipMemsetAsync).
// ---------------------------------------------------------------------------
__global__ void zero_out2(float* __restrict__ out2, int n)
{
    int i = blockIdx.x * blockDim.x + threadIdx.x;
    if (i < n) out2[i] = 0.0f;
}

// ---------------------------------------------------------------------------
extern "C" void kernel_launch(void* const* d_in, const int* in_sizes, int n_in,
                              void* d_out, int out_size, void* d_ws, size_t ws_size,
                              hipStream_t stream)
{
    const float* inputs  = (const float*)d_in[0];  // [16,512,128]
    const float* enc_W   = (const float*)d_in[1];  // [128,1024]
    const float* enc_b   = (const float*)d_in[2];  // [1024]
    const float* W_cells = (const float*)d_in[3];  // [2,1024,1024]
    const float* b_cells = (const float*)d_in[4];  // [2,1024]

    const int B = 16, L = 512, C = 128, D = 1024;
    const int M = B * L;  // 8192

    // ws: s1 i8 4MB | W1h/l 0.5MB | W2h/l 4MB | W3h/l 4MB | h0 32MB | h1 32MB
    char* ws = (char*)d_ws;
    size_t off = 0;
    uint8_t* s1 = (uint8_t*)(ws + off);
    off += (size_t)(M / 32) * (C / 16) * 4 * 32 * 16;
    bf16_t* W1h = (bf16_t*)(ws + off); off += (size_t)C * D * 2;
    bf16_t* W1l = (bf16_t*)(ws + off); off += (size_t)C * D * 2;
    bf16_t* W2h = (bf16_t*)(ws + off); off += (size_t)D * D * 2;
    bf16_t* W2l = (bf16_t*)(ws + off); off += (size_t)D * D * 2;
    bf16_t* W3h = (bf16_t*)(ws + off); off += (size_t)D * D * 2;
    bf16_t* W3l = (bf16_t*)(ws + off); off += (size_t)D * D * 2;
    uint8_t* h0 = (uint8_t*)(ws + off);
    off += (size_t)(M / 32) * (D / 16) * 4 * 32 * 16;
    uint8_t* h1 = (uint8_t*)(ws + off);

    float* out  = (float*)d_out;          // [M, D]
    float* out2 = out + (size_t)M * D;    // [B, D]

    split_transpose_all<<<dim3(32, 32, 3), 256, 0, stream>>>(
        enc_W, W_cells, W1h, W1l, W2h, W2l, W3h, W3l);

    spike_encode_i8<<<256, 256, 0, stream>>>(inputs, (uint4*)s1);

    zero_out2<<<(B * D + 255) / 256, 256, 0, stream>>>(out2, B * D);

    const int nblocks = (M / 64) * (D / 64);   // 2048
    gemm_lif_mfma<128, false><<<nblocks, 256, 0, stream>>>(
        s1, W1h, W1l, enc_b, h0, nullptr, M, D);
    gemm_lif_mfma<1024, false><<<nblocks, 256, 0, stream>>>(
        h0, W2h, W2l, b_cells, h1, nullptr, M, D);
    gemm_lif_mfma<1024, true><<<nblocks, 256, 0, stream>>>(
        h1, W3h, W3l, b_cells + D, nullptr, out, M, D);
}

// Round 11
// 279.254 us; speedup vs baseline: 1.1018x; 1.1018x over previous
//
#include <hip/hip_runtime.h>
#include <hip/hip_bf16.h>
#include <stdint.h>

#define TSTEPS 4

typedef __bf16 bf16_t;
typedef __attribute__((ext_vector_type(8))) __bf16 bf16x8;
typedef __attribute__((ext_vector_type(16))) float f32x16;
typedef __attribute__((ext_vector_type(4))) unsigned short ushort4v;

union frag_u { bf16x8 v; uint32_t d[4]; unsigned short u[8]; };

// gfx9 s_waitcnt imm: vm [3:0]|[15:14]; exp [6:4]; lgkm [11:8].
#define WT_VM2_LG0  0x072   // vmcnt(2) lgkmcnt(0)
#define WT_VM2      0xF72   // vmcnt(2)
#define WT_LG0      0xC07F  // lgkmcnt(0), vm unbounded
#define WT_VM0_LG0  0x070   // full drain (tail)

// ---------------------------------------------------------------------------
// R27: FULL-LDS operand staging (m97-faithful). Six schedule variants
// (R18-R26) all pin at 46-48% MfmaUtil with ~1300-1700cy per 8-MFMA wave
// step; the residual ~1000cy is insensitive to prefetch depth, barriers,
// phase size, VALU count, and byte volume. Last untested difference vs the
// guide's proven ladder: VMEM op count. We always kept 4-6 GLOBAL loads per
// wave-step (A to regs); m97 keeps 2 (global_load_lds only), rest ds_read.
// This round: A AND B staged via global_load_lds (8x1KB chunks/kb: A 2x2KB,
// B 2x2KB; 2 chunks/wave), ring-4 LDS slabs (32KB), one barrier/step,
// vmcnt(2) counted wait (never 0 mid-loop), fragments via 4x ds_read_b64
// (A per t) + 2x ds_read_b128 (B), hoisted after the barrier, drained by
// next step's lgkm(0). Per wave-step: 2 VMEM + 6 DS (was 5 VMEM + 2 DS).
// A now LDS-deduped across the two m-waves.
// Spike bytes 0x3F -> v_perm high-byte = bf16 0.5; B pre-doubled (exact
// exponent bump) so products are bitwise 1.0*w (R19/R21/R22-proven).
// A layout: [m_blk32][kb16][t][row0..31][16 bytes], byte = 0x00 / 0x3F.
// B-frag layout: packet ((n>>5)*NKB + (k>>4))*512 + ((n&31)+32*((k>>3)&1))*8
// + (k&7), bf16, value = 2*w_hi / 2*w_lo.
// Fused mean-over-L in LAST epilogue kept (R24 win).
// ---------------------------------------------------------------------------

// ---------------------------------------------------------------------------
// Stage 1: input LIF encoder -> spike 0x3F bytes. C=128. XLA-exact LIF.
// ---------------------------------------------------------------------------
__global__ void spike_encode_i8(const float* __restrict__ x,
                                uint4* __restrict__ s1)
{
    const int C = 128;
    int tid = blockIdx.x * blockDim.x + threadIdx.x;  // 65536 = 256*8*32
    int row = tid & 31;
    int kb  = (tid >> 5) & 7;
    int m_blk = tid >> 8;
    int m = m_blk * 32 + row;
    const float* px = x + (size_t)m * C + kb * 16;
    float xv[16];
#pragma unroll
    for (int j = 0; j < 16; j += 4) {
        float4 t4 = *(const float4*)(px + j);
        xv[j] = t4.x; xv[j+1] = t4.y; xv[j+2] = t4.z; xv[j+3] = t4.w;
    }
    float v[16];
#pragma unroll
    for (int j = 0; j < 16; ++j) v[j] = 0.0f;
#pragma unroll
    for (int t = 0; t < TSTEPS; ++t) {
        uint32_t dw[4] = {0u, 0u, 0u, 0u};
#pragma unroll
        for (int j = 0; j < 16; ++j) {
            float vv = __fadd_rn(v[j], __fmul_rn(__fsub_rn(xv[j], v[j]), 0.5f));
            bool sp = (vv >= 1.0f);
            dw[j >> 2] |= sp ? (0x3Fu << ((j & 3) * 8)) : 0u;
            v[j] = sp ? 0.0f : vv;
        }
        uint4 o; o.x = dw[0]; o.y = dw[1]; o.z = dw[2]; o.w = dw[3];
        s1[((size_t)(m_blk * 8 + kb) * 4 + t) * 32 + row] = o;
    }
}

// ---------------------------------------------------------------------------
// Weight prep: W [K][N] fp32 -> 2*hi / 2*lo bf16 split in B-frag layout.
// ---------------------------------------------------------------------------
__global__ void split_transpose_all(const float* __restrict__ enc_W,
                                    const float* __restrict__ W_cells,
                                    bf16_t* __restrict__ W1h, bf16_t* __restrict__ W1l,
                                    bf16_t* __restrict__ W2h, bf16_t* __restrict__ W2l,
                                    bf16_t* __restrict__ W3h, bf16_t* __restrict__ W3l)
{
    const int N = 1024;
    const float* W;
    bf16_t *hi, *lo;
    int K;
    if (blockIdx.z == 0) {
        if (blockIdx.x >= 4) return;
        W = enc_W; hi = W1h; lo = W1l; K = 128;
    } else if (blockIdx.z == 1) {
        W = W_cells; hi = W2h; lo = W2l; K = 1024;
    } else {
        W = W_cells + (size_t)1024 * 1024; hi = W3h; lo = W3l; K = 1024;
    }
    const int NKB = K >> 4;
    __shared__ float tile[32][33];
    int k0 = blockIdx.x * 32, n0 = blockIdx.y * 32;
    int tx = threadIdx.x & 31, ty = threadIdx.x >> 5;
    for (int kk = ty; kk < 32; kk += 8)
        tile[kk][tx] = W[(size_t)(k0 + kk) * N + n0 + tx];
    __syncthreads();

    const int nn = tx;
    const int oc = ty;            // 0..7
    const int o2 = oc & 3;        // k-octet
    const bool isLo = (oc >> 2) != 0;
    const int kblk = (k0 >> 4) + (o2 >> 1);
    const int lane_in_packet = nn + 32 * (o2 & 1);

    frag_u f;
#pragma unroll
    for (int j = 0; j < 8; ++j) {
        float wv = tile[o2 * 8 + j][nn];
        bf16_t h = (bf16_t)wv;                          // original hi rounding
        bf16_t l = (bf16_t)(wv - (float)h);             // original lo rounding
        f.v[j] = isLo ? (bf16_t)(2.0f * (float)l)       // exact doubling
                      : (bf16_t)(2.0f * (float)h);
    }
    bf16_t* dst = (isLo ? lo : hi)
        + ((size_t)((n0 + nn) >> 5) * NKB + kblk) * 512 + lane_in_packet * 8;
    *(bf16x8*)dst = f.v;
}

// ---------------------------------------------------------------------------
// Fused MFMA GEMM + multistep LIF. R27: full-LDS staging (A+B via
// global_load_lds, ring-4), 2 VMEM + 6 DS per wave-step, counted waits,
// fused mean (LAST).
// ---------------------------------------------------------------------------
template <int K, bool LAST>
__global__ __launch_bounds__(256, 4)
void gemm_lif_mfma(const uint8_t* __restrict__ Abytes,
                   const bf16_t* __restrict__ Bh,
                   const bf16_t* __restrict__ Bl,
                   const float* __restrict__ bias,
                   uint8_t* __restrict__ Sbytes,
                   float* __restrict__ Out,
                   int M, int N)
{
    constexpr int NKB = K >> 4;                 // 8 or 64 (>= 4, even)
    // Ring slab (8KB/kb): [A m_local0 2KB | A m_local1 2KB |
    //                      B n0 hi 1KB | B n0 lo 1KB | B n1 hi | B n1 lo]
    __shared__ __align__(16) uint8_t ldsR[4][8192];      // 32KB ring
    __shared__ __align__(8) unsigned short sh[4][256];   // epilogue, per-wave

    const int tid = threadIdx.x;
    const int lane = tid & 63;
    const int wid = tid >> 6;
    const int l31 = lane & 31;
    const int half = lane >> 5;

    // XCD-locality swizzle (R18): XCD x owns m_t in [x*16, x*16+16);
    // walk nh(2) x mloc(16) x n8(8). Bijective.
    const int bid = blockIdx.x;
    const int xcd = bid & 7;
    const int j   = bid >> 3;                   // 0..255
    const int nh   = j >> 7;                    // 0..1
    const int r    = j & 127;
    const int mloc = r >> 3;                    // 0..15
    const int n_t  = nh * 8 + (r & 7);          // 0..15
    const int m_t  = xcd * 16 + mloc;           // 0..127

    const int m0 = m_t * 64, n0 = n_t * 64;
    const int wave_m = (wid & 1) * 32;
    const int wave_n = (wid >> 1) * 32;
    const int m_blk = (m0 + wave_m) >> 5;

    // ---- staging assignment: wave wid stages 2 of the 8 1KB chunks ----
    const uint8_t* src0;
    const uint8_t* src1;
    int sstride, d0off, d1off;
    if (wid < 2) {
        // A chunks: m_local = wid; 2KB/kb contiguous ([t][row][16B])
        const uint8_t* base = Abytes + ((size_t)(m0 >> 5) + wid) * NKB * 2048;
        src0 = base + (lane << 4);
        src1 = base + 1024 + (lane << 4);
        sstride = 2048;
        d0off = wid * 2048;
        d1off = d0off + 1024;
    } else {
        // B chunks: n_local = wid-2; hi and lo planes, 1KB/kb each
        const int nl = wid - 2;
        src0 = (const uint8_t*)(Bh + ((size_t)(n0 >> 5) + nl) * NKB * 512)
               + (lane << 4);
        src1 = (const uint8_t*)(Bl + ((size_t)(n0 >> 5) + nl) * NKB * 512)
               + (lane << 4);
        sstride = 1024;
        d0off = 4096 + nl * 2048;
        d1off = d0off + 1024;
    }
    uint8_t* ringBase = &ldsR[0][0];

    // ---- consumer fragment addresses ----
    // A: slot + (wid&1)*2048 + t*512 + l31*16 + half*8  (uint2 per t)
    // B: slot + 4096 + (wid>>1)*2048 (+1024 lo) + lane*16 (bf16x8)
    const int aRdOff = (wid & 1) * 2048 + l31 * 16 + half * 8;
    const int bRdOff = 4096 + ((wid >> 1) << 11) + (lane << 4);

    f32x16 acc[TSTEPS];
#pragma unroll
    for (int t = 0; t < TSTEPS; ++t)
        for (int rr = 0; rr < 16; ++rr) acc[t][rr] = 0.0f;

    uint2 fm[4];
    bf16x8 cfh, cfl;

#define STAGE2(kb_) {                                                         \
    __builtin_amdgcn_global_load_lds(                                         \
        (const __attribute__((address_space(1))) uint32_t*)                   \
            (src0 + (size_t)(kb_) * sstride),                                 \
        (__attribute__((address_space(3))) uint32_t*)                         \
            (ringBase + (((kb_) & 3) << 13) + d0off),                         \
        16, 0, 0);                                                            \
    __builtin_amdgcn_global_load_lds(                                         \
        (const __attribute__((address_space(1))) uint32_t*)                   \
            (src1 + (size_t)(kb_) * sstride),                                 \
        (__attribute__((address_space(3))) uint32_t*)                         \
            (ringBase + (((kb_) & 3) << 13) + d1off),                         \
        16, 0, 0);                                                            \
    }

#define FRAGRD(kb_) {                                                        \
        const uint8_t* sb = ringBase + (((kb_) & 3) << 13);                  \
        fm[0] = *(const uint2*)(sb + aRdOff);                                \
        fm[1] = *(const uint2*)(sb + aRdOff + 512);                          \
        fm[2] = *(const uint2*)(sb + aRdOff + 1024);                         \
        fm[3] = *(const uint2*)(sb + aRdOff + 1536);                         \
        cfh = *(const bf16x8*)(sb + bRdOff);                                 \
        cfl = *(const bf16x8*)(sb + bRdOff + 1024);                          \
    }

// byte 0x3F -> high byte of each 16-bit half = 0x3F00 = bf16 0.5 (1 perm/dw)
#define EXPANDF(a_, f_) {                                                    \
        (f_).d[0] = __builtin_amdgcn_perm((a_).x, 0u, 0x05000400u);          \
        (f_).d[1] = __builtin_amdgcn_perm((a_).x, 0u, 0x07000600u);          \
        (f_).d[2] = __builtin_amdgcn_perm((a_).y, 0u, 0x05000400u);          \
        (f_).d[3] = __builtin_amdgcn_perm((a_).y, 0u, 0x07000600u);          \
    }

#define MFMAS() {                                                            \
        frag_u af0, af1, af2, af3;                                           \
        EXPANDF(fm[0], af0);                                                 \
        EXPANDF(fm[1], af1);                                                 \
        EXPANDF(fm[2], af2);                                                 \
        EXPANDF(fm[3], af3);                                                 \
        acc[0] = __builtin_amdgcn_mfma_f32_32x32x16_bf16(af0.v, cfh, acc[0], 0, 0, 0); \
        acc[1] = __builtin_amdgcn_mfma_f32_32x32x16_bf16(af1.v, cfh, acc[1], 0, 0, 0); \
        acc[2] = __builtin_amdgcn_mfma_f32_32x32x16_bf16(af2.v, cfh, acc[2], 0, 0, 0); \
        acc[3] = __builtin_amdgcn_mfma_f32_32x32x16_bf16(af3.v, cfh, acc[3], 0, 0, 0); \
        acc[0] = __builtin_amdgcn_mfma_f32_32x32x16_bf16(af0.v, cfl, acc[0], 0, 0, 0); \
        acc[1] = __builtin_amdgcn_mfma_f32_32x32x16_bf16(af1.v, cfl, acc[1], 0, 0, 0); \
        acc[2] = __builtin_amdgcn_mfma_f32_32x32x16_bf16(af2.v, cfl, acc[2], 0, 0, 0); \
        acc[3] = __builtin_amdgcn_mfma_f32_32x32x16_bf16(af3.v, cfl, acc[3], 0, 0, 0); \
    }

    // Prologue: stage kb 0,1 (slots 0,1); drain stage(0); read frags(0).
    STAGE2(0);
    STAGE2(1);
    __builtin_amdgcn_s_waitcnt(WT_VM2);      // drains stage(0)
    asm volatile("" ::: "memory");
    __builtin_amdgcn_s_barrier();
    asm volatile("" ::: "memory");
    FRAGRD(0);

    // Steady state: step kb computes kb, stages kb+2, publishes kb+1.
    // vmcnt(2): outstanding = stage(kb+1) 2 + stage(kb+2) 2 -> drains
    // stage(kb+1) (one full step of latency cover). lgkm(0): drains the
    // hoisted frag reads for kb. Barrier publishes slot (kb+1)&3 (every
    // wave drained its own stage(kb+1) writes before arriving).
    // Ring reuse: slot (kb+2)&3 held kb-2, whose ds_reads were lgkm-drained
    // two barriers before this STAGE2 issues.
    for (int kb = 0; kb < NKB - 2; ++kb) {
        STAGE2(kb + 2);
        __builtin_amdgcn_s_waitcnt(WT_VM2_LG0);
        asm volatile("" ::: "memory");
        MFMAS();
        __builtin_amdgcn_s_barrier();
        asm volatile("" ::: "memory");
        FRAGRD(kb + 1);
    }
    // Step NKB-2: nothing to stage; drain stage(NKB-1) + frag reads.
    __builtin_amdgcn_s_waitcnt(WT_VM0_LG0);
    asm volatile("" ::: "memory");
    MFMAS();
    __builtin_amdgcn_s_barrier();
    asm volatile("" ::: "memory");
    FRAGRD(NKB - 1);
    // Step NKB-1: final.
    __builtin_amdgcn_s_waitcnt(WT_LG0);
    asm volatile("" ::: "memory");
    MFMAS();

#undef MFMAS
#undef EXPANDF
#undef FRAGRD
#undef STAGE2

    // --- LIF epilogue: t-scan in registers (XLA-exact arithmetic) ---
    const float bv = bias[n0 + wave_n + l31];
    f32x16 vmem;
#pragma unroll
    for (int rr = 0; rr < 16; ++rr) vmem[rr] = 0.0f;
    uint64_t bits = 0ull;
    unsigned short* myt = &sh[wid][0];          // [row][kb][t] = [32][2][4]

    const int NKBo = N >> 4;
    const int kbase = (n0 + wave_n) >> 4;

    for (int t = 0; t < TSTEPS; ++t) {
#pragma unroll
        for (int rr = 0; rr < 16; ++rr) {
            float y = __fadd_rn(acc[t][rr], bv);
            float vv = vmem[rr];
            vv = __fadd_rn(vv, __fmul_rn(__fsub_rn(y, vv), 0.5f));
            bool sp = (vv >= 1.0f);
            vmem[rr] = sp ? 0.0f : vv;
            if (LAST) {
                bits |= sp ? (1ull << (rr * 4 + t)) : 0ull;
            } else {
                unsigned long long b = __ballot(sp);
                if (l31 == 0) {
                    uint32_t hb = (uint32_t)(b >> (half * 32));
                    int rowi = (rr & 3) + 8 * (rr >> 2) + 4 * half;
                    myt[(rowi * 2 + 0) * 4 + t] = (unsigned short)hb;
                    myt[(rowi * 2 + 1) * 4 + t] = (unsigned short)(hb >> 16);
                }
            }
        }
    }

    if (LAST) {
        // Out writes + fused mean-over-L. All values multiples of 2^-11,
        // totals <= 1 -> fp32 atomics exact and order-independent.
        float psum = 0.0f;
#pragma unroll
        for (int rr = 0; rr < 16; ++rr) {
            int m_r = (rr & 3) + 8 * (rr >> 2) + 4 * half;
            int m = m0 + wave_m + m_r;
            int n = n0 + wave_n + l31;
            int cnt = __popc((unsigned)((bits >> (rr * 4)) & 0xFull));
            float val = 0.25f * (float)cnt;
            Out[(size_t)m * N + n] = val;
            psum += val;                       // exact: multiples of 0.25
        }
        // combine the two halves (same n, other 16 m's of the 32-row blk)
        psum += __shfl_xor(psum, 32, 64);
        if (half == 0) {
            float* out2 = Out + (size_t)M * N;
            int b = m0 >> 9;                   // m0 multiple of 64; L = 512
            int n = n0 + wave_n + l31;
            atomicAdd(out2 + (size_t)b * N + n, psum * (1.0f / 512.0f));
        }
    } else {
        // Emit next-stage A bytes: 0x00 / 0x3F.
        const ushort4v pk = *(const ushort4v*)&myt[(l31 * 2 + half) * 4];
#pragma unroll
        for (int t = 0; t < TSTEPS; ++t) {
            uint32_t m16 = pk[t];
            uint4 o;
            o.x = (((m16      ) & 0xFu) * 0x00204081u & 0x01010101u) * 0x3Fu;
            o.y = (((m16 >>  4) & 0xFu) * 0x00204081u & 0x01010101u) * 0x3Fu;
            o.z = (((m16 >>  8) & 0xFu) * 0x00204081u & 0x01010101u) * 0x3Fu;
            o.w = (((m16 >> 12) & 0xFu) * 0x00204081u & 0x01010101u) * 0x3Fu;
            *(uint4*)(Sbytes + ((((size_t)m_blk * NKBo + kbase + half) * 4 + t)
                                * 32 + l31) * 16) = o;
        }
    }
}

// ---------------------------------------------------------------------------
// Zero out2 (graph-capture-safe replacement for hipMemsetAsync).
// ---------------------------------------------------------------------------
__global__ void zero_out2(float* __restrict__ out2, int n)
{
    int i = blockIdx.x * blockDim.x + threadIdx.x;
    if (i < n) out2[i] = 0.0f;
}

// ---------------------------------------------------------------------------
extern "C" void kernel_launch(void* const* d_in, const int* in_sizes, int n_in,
                              void* d_out, int out_size, void* d_ws, size_t ws_size,
                              hipStream_t stream)
{
    const float* inputs  = (const float*)d_in[0];  // [16,512,128]
    const float* enc_W   = (const float*)d_in[1];  // [128,1024]
    const float* enc_b   = (const float*)d_in[2];  // [1024]
    const float* W_cells = (const float*)d_in[3];  // [2,1024,1024]
    const float* b_cells = (const float*)d_in[4];  // [2,1024]

    const int B = 16, L = 512, C = 128, D = 1024;
    const int M = B * L;  // 8192

    // ws: s1 i8 4MB | W1h/l 0.5MB | W2h/l 4MB | W3h/l 4MB | h0 32MB | h1 32MB
    char* ws = (char*)d_ws;
    size_t off = 0;
    uint8_t* s1 = (uint8_t*)(ws + off);
    off += (size_t)(M / 32) * (C / 16) * 4 * 32 * 16;
    bf16_t* W1h = (bf16_t*)(ws + off); off += (size_t)C * D * 2;
    bf16_t* W1l = (bf16_t*)(ws + off); off += (size_t)C * D * 2;
    bf16_t* W2h = (bf16_t*)(ws + off); off += (size_t)D * D * 2;
    bf16_t* W2l = (bf16_t*)(ws + off); off += (size_t)D * D * 2;
    bf16_t* W3h = (bf16_t*)(ws + off); off += (size_t)D * D * 2;
    bf16_t* W3l = (bf16_t*)(ws + off); off += (size_t)D * D * 2;
    uint8_t* h0 = (uint8_t*)(ws + off);
    off += (size_t)(M / 32) * (D / 16) * 4 * 32 * 16;
    uint8_t* h1 = (uint8_t*)(ws + off);

    float* out  = (float*)d_out;          // [M, D]
    float* out2 = out + (size_t)M * D;    // [B, D]

    split_transpose_all<<<dim3(32, 32, 3), 256, 0, stream>>>(
        enc_W, W_cells, W1h, W1l, W2h, W2l, W3h, W3l);

    spike_encode_i8<<<256, 256, 0, stream>>>(inputs, (uint4*)s1);

    zero_out2<<<(B * D + 255) / 256, 256, 0, stream>>>(out2, B * D);

    const int nblocks = (M / 64) * (D / 64);   // 2048
    gemm_lif_mfma<128, false><<<nblocks, 256, 0, stream>>>(
        s1, W1h, W1l, enc_b, h0, nullptr, M, D);
    gemm_lif_mfma<1024, false><<<nblocks, 256, 0, stream>>>(
        h0, W2h, W2l, b_cells, h1, nullptr, M, D);
    gemm_lif_mfma<1024, true><<<nblocks, 256, 0, stream>>>(
        h1, W3h, W3l, b_cells + D, nullptr, out, M, D);
}

// Round 12
// 278.186 us; speedup vs baseline: 1.1060x; 1.0038x over previous
//
#include <hip/hip_runtime.h>
#include <hip/hip_bf16.h>
#include <stdint.h>

#define TSTEPS 4

typedef __bf16 bf16_t;
typedef __attribute__((ext_vector_type(8))) __bf16 bf16x8;
typedef __attribute__((ext_vector_type(16))) float f32x16;
typedef __attribute__((ext_vector_type(4))) unsigned short ushort4v;

union frag_u { bf16x8 v; uint32_t d[4]; unsigned short u[8]; };

// gfx9 s_waitcnt imm: vm [3:0]|[15:14]; exp [6:4]; lgkm [11:8].
#define WT_VM2_LG0  0x072   // vmcnt(2) lgkmcnt(0)
#define WT_VM2      0xF72   // vmcnt(2)
#define WT_LG0      0xC07F  // lgkmcnt(0), vm unbounded
#define WT_VM0_LG0  0x070   // full drain (tail)

// ---------------------------------------------------------------------------
// R28 = R27 (full-LDS staging, 2 VMEM + 6 DS per wave-step -> 55% MfmaUtil,
// the round that broke the 47% plateau) + A-packet bank-conflict fix.
// R27 symptom: SQ_LDS_BANK_CONFLICT 16K -> 8.4M. Cause: A ds_read_b64 at
// l31*16 + half*8 -> 16B stride within a 32-lane group -> 8 banks, 4
// lanes/bank (4-way, 1.58x per m136). Fix: A packet reordered
// [t][row][16B] -> [t][half][row][8B]; consumer reads half*256 + l31*8 ->
// banks 0..31 covered exactly 2x per 32-lane group (2-way = free).
// global_load_lds copies bytes linearly, so only the PRODUCERS change
// (spike_encode + epilogue emit 2x uint2 instead of 1x uint4); the 8 bytes
// each lane consumes are bitwise identical -> absmax 0 preserved.
// Spike bytes 0x3F -> v_perm high-byte = bf16 0.5; B pre-doubled (exact
// exponent bump) so products are bitwise 1.0*w (R19/R21/R22-proven).
// A layout: [m_blk32][kb16][t][half][row0..31][8 bytes], byte = 0x00/0x3F.
// B-frag layout: packet ((n>>5)*NKB + (k>>4))*512 + ((n&31)+32*((k>>3)&1))*8
// + (k&7), bf16, value = 2*w_hi / 2*w_lo.
// Fused mean-over-L in LAST epilogue kept (R24 win).
// ---------------------------------------------------------------------------

// ---------------------------------------------------------------------------
// Stage 1: input LIF encoder -> spike 0x3F bytes. C=128. XLA-exact LIF.
// ---------------------------------------------------------------------------
__global__ void spike_encode_i8(const float* __restrict__ x,
                                uint8_t* __restrict__ s1)
{
    const int C = 128;
    int tid = blockIdx.x * blockDim.x + threadIdx.x;  // 65536 = 256*8*32
    int row = tid & 31;
    int kb  = (tid >> 5) & 7;
    int m_blk = tid >> 8;
    int m = m_blk * 32 + row;
    const float* px = x + (size_t)m * C + kb * 16;
    float xv[16];
#pragma unroll
    for (int j = 0; j < 16; j += 4) {
        float4 t4 = *(const float4*)(px + j);
        xv[j] = t4.x; xv[j+1] = t4.y; xv[j+2] = t4.z; xv[j+3] = t4.w;
    }
    float v[16];
#pragma unroll
    for (int j = 0; j < 16; ++j) v[j] = 0.0f;
    uint8_t* pkt0 = s1 + (size_t)(m_blk * 8 + kb) * 4 * 512;
#pragma unroll
    for (int t = 0; t < TSTEPS; ++t) {
        uint32_t dw[4] = {0u, 0u, 0u, 0u};
#pragma unroll
        for (int j = 0; j < 16; ++j) {
            float vv = __fadd_rn(v[j], __fmul_rn(__fsub_rn(xv[j], v[j]), 0.5f));
            bool sp = (vv >= 1.0f);
            dw[j >> 2] |= sp ? (0x3Fu << ((j & 3) * 8)) : 0u;
            v[j] = sp ? 0.0f : vv;
        }
        // [t][half][row][8B]: k0-7 at row*8, k8-15 at 256+row*8
        uint2 lo2; lo2.x = dw[0]; lo2.y = dw[1];
        uint2 hi2; hi2.x = dw[2]; hi2.y = dw[3];
        *(uint2*)(pkt0 + (size_t)t * 512 + row * 8)       = lo2;
        *(uint2*)(pkt0 + (size_t)t * 512 + 256 + row * 8) = hi2;
    }
}

// ---------------------------------------------------------------------------
// Weight prep: W [K][N] fp32 -> 2*hi / 2*lo bf16 split in B-frag layout.
// ---------------------------------------------------------------------------
__global__ void split_transpose_all(const float* __restrict__ enc_W,
                                    const float* __restrict__ W_cells,
                                    bf16_t* __restrict__ W1h, bf16_t* __restrict__ W1l,
                                    bf16_t* __restrict__ W2h, bf16_t* __restrict__ W2l,
                                    bf16_t* __restrict__ W3h, bf16_t* __restrict__ W3l)
{
    const int N = 1024;
    const float* W;
    bf16_t *hi, *lo;
    int K;
    if (blockIdx.z == 0) {
        if (blockIdx.x >= 4) return;
        W = enc_W; hi = W1h; lo = W1l; K = 128;
    } else if (blockIdx.z == 1) {
        W = W_cells; hi = W2h; lo = W2l; K = 1024;
    } else {
        W = W_cells + (size_t)1024 * 1024; hi = W3h; lo = W3l; K = 1024;
    }
    const int NKB = K >> 4;
    __shared__ float tile[32][33];
    int k0 = blockIdx.x * 32, n0 = blockIdx.y * 32;
    int tx = threadIdx.x & 31, ty = threadIdx.x >> 5;
    for (int kk = ty; kk < 32; kk += 8)
        tile[kk][tx] = W[(size_t)(k0 + kk) * N + n0 + tx];
    __syncthreads();

    const int nn = tx;
    const int oc = ty;            // 0..7
    const int o2 = oc & 3;        // k-octet
    const bool isLo = (oc >> 2) != 0;
    const int kblk = (k0 >> 4) + (o2 >> 1);
    const int lane_in_packet = nn + 32 * (o2 & 1);

    frag_u f;
#pragma unroll
    for (int j = 0; j < 8; ++j) {
        float wv = tile[o2 * 8 + j][nn];
        bf16_t h = (bf16_t)wv;                          // original hi rounding
        bf16_t l = (bf16_t)(wv - (float)h);             // original lo rounding
        f.v[j] = isLo ? (bf16_t)(2.0f * (float)l)       // exact doubling
                      : (bf16_t)(2.0f * (float)h);
    }
    bf16_t* dst = (isLo ? lo : hi)
        + ((size_t)((n0 + nn) >> 5) * NKB + kblk) * 512 + lane_in_packet * 8;
    *(bf16x8*)dst = f.v;
}

// ---------------------------------------------------------------------------
// Fused MFMA GEMM + multistep LIF. R28: full-LDS staging (ring-4), A packet
// [t][half][row][8B] (conflict-free ds_read_b64), counted waits, fused
// mean (LAST).
// ---------------------------------------------------------------------------
template <int K, bool LAST>
__global__ __launch_bounds__(256, 4)
void gemm_lif_mfma(const uint8_t* __restrict__ Abytes,
                   const bf16_t* __restrict__ Bh,
                   const bf16_t* __restrict__ Bl,
                   const float* __restrict__ bias,
                   uint8_t* __restrict__ Sbytes,
                   float* __restrict__ Out,
                   int M, int N)
{
    constexpr int NKB = K >> 4;                 // 8 or 64 (>= 4, even)
    // Ring slab (8KB/kb): [A m_local0 2KB | A m_local1 2KB |
    //                      B n0 hi 1KB | B n0 lo 1KB | B n1 hi | B n1 lo]
    __shared__ __align__(16) uint8_t ldsR[4][8192];      // 32KB ring
    __shared__ __align__(8) unsigned short sh[4][256];   // epilogue, per-wave

    const int tid = threadIdx.x;
    const int lane = tid & 63;
    const int wid = tid >> 6;
    const int l31 = lane & 31;
    const int half = lane >> 5;

    // XCD-locality swizzle (R18): XCD x owns m_t in [x*16, x*16+16);
    // walk nh(2) x mloc(16) x n8(8). Bijective.
    const int bid = blockIdx.x;
    const int xcd = bid & 7;
    const int j   = bid >> 3;                   // 0..255
    const int nh   = j >> 7;                    // 0..1
    const int r    = j & 127;
    const int mloc = r >> 3;                    // 0..15
    const int n_t  = nh * 8 + (r & 7);          // 0..15
    const int m_t  = xcd * 16 + mloc;           // 0..127

    const int m0 = m_t * 64, n0 = n_t * 64;
    const int wave_m = (wid & 1) * 32;
    const int wave_n = (wid >> 1) * 32;
    const int m_blk = (m0 + wave_m) >> 5;

    // ---- staging assignment: wave wid stages 2 of the 8 1KB chunks ----
    const uint8_t* src0;
    const uint8_t* src1;
    int sstride, d0off, d1off;
    if (wid < 2) {
        // A chunks: m_local = wid; 2KB/kb contiguous ([t][half][row][8B])
        const uint8_t* base = Abytes + ((size_t)(m0 >> 5) + wid) * NKB * 2048;
        src0 = base + (lane << 4);
        src1 = base + 1024 + (lane << 4);
        sstride = 2048;
        d0off = wid * 2048;
        d1off = d0off + 1024;
    } else {
        // B chunks: n_local = wid-2; hi and lo planes, 1KB/kb each
        const int nl = wid - 2;
        src0 = (const uint8_t*)(Bh + ((size_t)(n0 >> 5) + nl) * NKB * 512)
               + (lane << 4);
        src1 = (const uint8_t*)(Bl + ((size_t)(n0 >> 5) + nl) * NKB * 512)
               + (lane << 4);
        sstride = 1024;
        d0off = 4096 + nl * 2048;
        d1off = d0off + 1024;
    }
    uint8_t* ringBase = &ldsR[0][0];

    // ---- consumer fragment addresses ----
    // A: slot + (wid&1)*2048 + t*512 + half*256 + l31*8  (uint2 per t)
    //    -> 32-lane group covers banks 0..31 exactly 2x: conflict-free.
    // B: slot + 4096 + (wid>>1)*2048 (+1024 lo) + lane*16 (bf16x8)
    const int aRdOff = (wid & 1) * 2048 + half * 256 + l31 * 8;
    const int bRdOff = 4096 + ((wid >> 1) << 11) + (lane << 4);

    f32x16 acc[TSTEPS];
#pragma unroll
    for (int t = 0; t < TSTEPS; ++t)
        for (int rr = 0; rr < 16; ++rr) acc[t][rr] = 0.0f;

    uint2 fm[4];
    bf16x8 cfh, cfl;

#define STAGE2(kb_) {                                                         \
    __builtin_amdgcn_global_load_lds(                                         \
        (const __attribute__((address_space(1))) uint32_t*)                   \
            (src0 + (size_t)(kb_) * sstride),                                 \
        (__attribute__((address_space(3))) uint32_t*)                         \
            (ringBase + (((kb_) & 3) << 13) + d0off),                         \
        16, 0, 0);                                                            \
    __builtin_amdgcn_global_load_lds(                                         \
        (const __attribute__((address_space(1))) uint32_t*)                   \
            (src1 + (size_t)(kb_) * sstride),                                 \
        (__attribute__((address_space(3))) uint32_t*)                         \
            (ringBase + (((kb_) & 3) << 13) + d1off),                         \
        16, 0, 0);                                                            \
    }

#define FRAGRD(kb_) {                                                        \
        const uint8_t* sb = ringBase + (((kb_) & 3) << 13);                  \
        fm[0] = *(const uint2*)(sb + aRdOff);                                \
        fm[1] = *(const uint2*)(sb + aRdOff + 512);                          \
        fm[2] = *(const uint2*)(sb + aRdOff + 1024);                         \
        fm[3] = *(const uint2*)(sb + aRdOff + 1536);                         \
        cfh = *(const bf16x8*)(sb + bRdOff);                                 \
        cfl = *(const bf16x8*)(sb + bRdOff + 1024);                          \
    }

// byte 0x3F -> high byte of each 16-bit half = 0x3F00 = bf16 0.5 (1 perm/dw)
#define EXPANDF(a_, f_) {                                                    \
        (f_).d[0] = __builtin_amdgcn_perm((a_).x, 0u, 0x05000400u);          \
        (f_).d[1] = __builtin_amdgcn_perm((a_).x, 0u, 0x07000600u);          \
        (f_).d[2] = __builtin_amdgcn_perm((a_).y, 0u, 0x05000400u);          \
        (f_).d[3] = __builtin_amdgcn_perm((a_).y, 0u, 0x07000600u);          \
    }

#define MFMAS() {                                                            \
        frag_u af0, af1, af2, af3;                                           \
        EXPANDF(fm[0], af0);                                                 \
        EXPANDF(fm[1], af1);                                                 \
        EXPANDF(fm[2], af2);                                                 \
        EXPANDF(fm[3], af3);                                                 \
        acc[0] = __builtin_amdgcn_mfma_f32_32x32x16_bf16(af0.v, cfh, acc[0], 0, 0, 0); \
        acc[1] = __builtin_amdgcn_mfma_f32_32x32x16_bf16(af1.v, cfh, acc[1], 0, 0, 0); \
        acc[2] = __builtin_amdgcn_mfma_f32_32x32x16_bf16(af2.v, cfh, acc[2], 0, 0, 0); \
        acc[3] = __builtin_amdgcn_mfma_f32_32x32x16_bf16(af3.v, cfh, acc[3], 0, 0, 0); \
        acc[0] = __builtin_amdgcn_mfma_f32_32x32x16_bf16(af0.v, cfl, acc[0], 0, 0, 0); \
        acc[1] = __builtin_amdgcn_mfma_f32_32x32x16_bf16(af1.v, cfl, acc[1], 0, 0, 0); \
        acc[2] = __builtin_amdgcn_mfma_f32_32x32x16_bf16(af2.v, cfl, acc[2], 0, 0, 0); \
        acc[3] = __builtin_amdgcn_mfma_f32_32x32x16_bf16(af3.v, cfl, acc[3], 0, 0, 0); \
    }

    // Prologue: stage kb 0,1 (slots 0,1); drain stage(0); read frags(0).
    STAGE2(0);
    STAGE2(1);
    __builtin_amdgcn_s_waitcnt(WT_VM2);      // drains stage(0)
    asm volatile("" ::: "memory");
    __builtin_amdgcn_s_barrier();
    asm volatile("" ::: "memory");
    FRAGRD(0);

    // Steady state: step kb computes kb, stages kb+2, publishes kb+1.
    // vmcnt(2): outstanding = stage(kb+1) 2 + stage(kb+2) 2 -> drains
    // stage(kb+1) (one full step of latency cover). lgkm(0): drains the
    // hoisted frag reads for kb. Barrier publishes slot (kb+1)&3 (every
    // wave drained its own stage(kb+1) writes before arriving).
    // Ring reuse: slot (kb+2)&3 held kb-2, whose ds_reads were lgkm-drained
    // two barriers before this STAGE2 issues.
    for (int kb = 0; kb < NKB - 2; ++kb) {
        STAGE2(kb + 2);
        __builtin_amdgcn_s_waitcnt(WT_VM2_LG0);
        asm volatile("" ::: "memory");
        MFMAS();
        __builtin_amdgcn_s_barrier();
        asm volatile("" ::: "memory");
        FRAGRD(kb + 1);
    }
    // Step NKB-2: nothing to stage; drain stage(NKB-1) + frag reads.
    __builtin_amdgcn_s_waitcnt(WT_VM0_LG0);
    asm volatile("" ::: "memory");
    MFMAS();
    __builtin_amdgcn_s_barrier();
    asm volatile("" ::: "memory");
    FRAGRD(NKB - 1);
    // Step NKB-1: final.
    __builtin_amdgcn_s_waitcnt(WT_LG0);
    asm volatile("" ::: "memory");
    MFMAS();

#undef MFMAS
#undef EXPANDF
#undef FRAGRD
#undef STAGE2

    // --- LIF epilogue: t-scan in registers (XLA-exact arithmetic) ---
    const float bv = bias[n0 + wave_n + l31];
    f32x16 vmem;
#pragma unroll
    for (int rr = 0; rr < 16; ++rr) vmem[rr] = 0.0f;
    uint64_t bits = 0ull;
    unsigned short* myt = &sh[wid][0];          // [row][kb][t] = [32][2][4]

    const int NKBo = N >> 4;
    const int kbase = (n0 + wave_n) >> 4;

    for (int t = 0; t < TSTEPS; ++t) {
#pragma unroll
        for (int rr = 0; rr < 16; ++rr) {
            float y = __fadd_rn(acc[t][rr], bv);
            float vv = vmem[rr];
            vv = __fadd_rn(vv, __fmul_rn(__fsub_rn(y, vv), 0.5f));
            bool sp = (vv >= 1.0f);
            vmem[rr] = sp ? 0.0f : vv;
            if (LAST) {
                bits |= sp ? (1ull << (rr * 4 + t)) : 0ull;
            } else {
                unsigned long long b = __ballot(sp);
                if (l31 == 0) {
                    uint32_t hb = (uint32_t)(b >> (half * 32));
                    int rowi = (rr & 3) + 8 * (rr >> 2) + 4 * half;
                    myt[(rowi * 2 + 0) * 4 + t] = (unsigned short)hb;
                    myt[(rowi * 2 + 1) * 4 + t] = (unsigned short)(hb >> 16);
                }
            }
        }
    }

    if (LAST) {
        // Out writes + fused mean-over-L. All values multiples of 2^-11,
        // totals <= 1 -> fp32 atomics exact and order-independent.
        float psum = 0.0f;
#pragma unroll
        for (int rr = 0; rr < 16; ++rr) {
            int m_r = (rr & 3) + 8 * (rr >> 2) + 4 * half;
            int m = m0 + wave_m + m_r;
            int n = n0 + wave_n + l31;
            int cnt = __popc((unsigned)((bits >> (rr * 4)) & 0xFull));
            float val = 0.25f * (float)cnt;
            Out[(size_t)m * N + n] = val;
            psum += val;                       // exact: multiples of 0.25
        }
        // combine the two halves (same n, other 16 m's of the 32-row blk)
        psum += __shfl_xor(psum, 32, 64);
        if (half == 0) {
            float* out2 = Out + (size_t)M * N;
            int b = m0 >> 9;                   // m0 multiple of 64; L = 512
            int n = n0 + wave_n + l31;
            atomicAdd(out2 + (size_t)b * N + n, psum * (1.0f / 512.0f));
        }
    } else {
        // Emit next-stage A in [t][half][row][8B] packet layout: thread
        // (l31 = row) writes k0-7 at row*8 and k8-15 at 256+row*8 within
        // packet [m_blk][kbase+half][t].
        const ushort4v pk = *(const ushort4v*)&myt[(l31 * 2 + half) * 4];
        uint8_t* pkt0 = Sbytes
            + ((size_t)m_blk * NKBo + kbase + half) * 4 * 512;
#pragma unroll
        for (int t = 0; t < TSTEPS; ++t) {
            uint32_t m16 = pk[t];
            uint32_t b0 = (((m16      ) & 0xFu) * 0x00204081u & 0x01010101u) * 0x3Fu;
            uint32_t b1 = (((m16 >>  4) & 0xFu) * 0x00204081u & 0x01010101u) * 0x3Fu;
            uint32_t b2 = (((m16 >>  8) & 0xFu) * 0x00204081u & 0x01010101u) * 0x3Fu;
            uint32_t b3 = (((m16 >> 12) & 0xFu) * 0x00204081u & 0x01010101u) * 0x3Fu;
            uint2 lo2; lo2.x = b0; lo2.y = b1;
            uint2 hi2; hi2.x = b2; hi2.y = b3;
            *(uint2*)(pkt0 + (size_t)t * 512 + l31 * 8)       = lo2;
            *(uint2*)(pkt0 + (size_t)t * 512 + 256 + l31 * 8) = hi2;
        }
    }
}

// ---------------------------------------------------------------------------
// Zero out2 (graph-capture-safe replacement for hipMemsetAsync).
// ---------------------------------------------------------------------------
__global__ void zero_out2(float* __restrict__ out2, int n)
{
    int i = blockIdx.x * blockDim.x + threadIdx.x;
    if (i < n) out2[i] = 0.0f;
}

// ---------------------------------------------------------------------------
extern "C" void kernel_launch(void* const* d_in, const int* in_sizes, int n_in,
                              void* d_out, int out_size, void* d_ws, size_t ws_size,
                              hipStream_t stream)
{
    const float* inputs  = (const float*)d_in[0];  // [16,512,128]
    const float* enc_W   = (const float*)d_in[1];  // [128,1024]
    const float* enc_b   = (const float*)d_in[2];  // [1024]
    const float* W_cells = (const float*)d_in[3];  // [2,1024,1024]
    const float* b_cells = (const float*)d_in[4];  // [2,1024]

    const int B = 16, L = 512, C = 128, D = 1024;
    const int M = B * L;  // 8192

    // ws: s1 i8 4MB | W1h/l 0.5MB | W2h/l 4MB | W3h/l 4MB | h0 32MB | h1 32MB
    char* ws = (char*)d_ws;
    size_t off = 0;
    uint8_t* s1 = (uint8_t*)(ws + off);
    off += (size_t)(M / 32) * (C / 16) * 4 * 32 * 16;
    bf16_t* W1h = (bf16_t*)(ws + off); off += (size_t)C * D * 2;
    bf16_t* W1l = (bf16_t*)(ws + off); off += (size_t)C * D * 2;
    bf16_t* W2h = (bf16_t*)(ws + off); off += (size_t)D * D * 2;
    bf16_t* W2l = (bf16_t*)(ws + off); off += (size_t)D * D * 2;
    bf16_t* W3h = (bf16_t*)(ws + off); off += (size_t)D * D * 2;
    bf16_t* W3l = (bf16_t*)(ws + off); off += (size_t)D * D * 2;
    uint8_t* h0 = (uint8_t*)(ws + off);
    off += (size_t)(M / 32) * (D / 16) * 4 * 32 * 16;
    uint8_t* h1 = (uint8_t*)(ws + off);

    float* out  = (float*)d_out;          // [M, D]
    float* out2 = out + (size_t)M * D;    // [B, D]

    split_transpose_all<<<dim3(32, 32, 3), 256, 0, stream>>>(
        enc_W, W_cells, W1h, W1l, W2h, W2l, W3h, W3l);

    spike_encode_i8<<<256, 256, 0, stream>>>(inputs, s1);

    zero_out2<<<(B * D + 255) / 256, 256, 0, stream>>>(out2, B * D);

    const int nblocks = (M / 64) * (D / 64);   // 2048
    gemm_lif_mfma<128, false><<<nblocks, 256, 0, stream>>>(
        s1, W1h, W1l, enc_b, h0, nullptr, M, D);
    gemm_lif_mfma<1024, false><<<nblocks, 256, 0, stream>>>(
        h0, W2h, W2l, b_cells, h1, nullptr, M, D);
    gemm_lif_mfma<1024, true><<<nblocks, 256, 0, stream>>>(
        h1, W3h, W3l, b_cells + D, nullptr, out, M, D);
}